// Round 1
// baseline (3713.202 us; speedup 1.0000x reference)
//
#include <hip/hip_runtime.h>
#include <hip/hip_bf16.h>
#include <float.h>

#define NPTS 262144
#define DDIM 128
#define NVQ 6
#define KCODES 512
#define TM 64
#define BLOCKT 256
#define CHUNK 64
#define NCHUNK (KCODES / CHUNK)
#define LDSPITCH 132   // 128 + 4 pad: breaks power-of-2 LDS bank strides

// ---------------------------------------------------------------------------
// Zero the commit-loss accumulator slot (must happen before atomicAdds).
__global__ void zero_commit_kernel(float* p) { *p = 0.0f; }

// ---------------------------------------------------------------------------
// norms[s*K + c] = sum_d E[s][c][d]^2. One wave per code row.
__global__ void norms_kernel(const float* __restrict__ cb, float* __restrict__ norms) {
    int row = blockIdx.x;            // 0 .. NVQ*KCODES-1
    int lane = threadIdx.x;          // 0 .. 63
    const float* r = cb + (size_t)row * DDIM;
    float2 v = *(const float2*)(r + lane * 2);
    float s = v.x * v.x + v.y * v.y;
    #pragma unroll
    for (int m = 32; m >= 1; m >>= 1) s += __shfl_xor(s, m);
    if (lane == 0) norms[row] = s;
}

// ---------------------------------------------------------------------------
// Fused residual-VQ (6 stages) + final linear.
// Block: 256 threads, tile of TM=64 points.
__global__ __launch_bounds__(BLOCKT, 2)
void rvq_kernel(const float* __restrict__ x, const float* __restrict__ cb,
                const float* __restrict__ W, const float* __restrict__ bias,
                const float* __restrict__ norms, float* __restrict__ out) {
    __shared__ float r_lds[TM][LDSPITCH];
    __shared__ float e_lds[CHUNK][LDSPITCH];
    __shared__ float cn[CHUNK];          // per-chunk code norms (or bias in linear)
    __shared__ float part[BLOCKT];
    __shared__ float rnorm[TM];
    __shared__ int   besti_lds[TM];

    const int tid = threadIdx.x;
    const int p0  = blockIdx.x * TM;
    const int tp  = tid >> 4;            // 0..15  (point group)
    const int tc  = tid & 15;            // 0..15  (code group)
    const int pown = tid >> 2;           // owned point for update/y (0..63)
    const int dq   = (tid & 3) * 32;     // owned d-quarter base

    // ---- load x tile into r_lds (coalesced float4) ----
    {
        const float* src = x + (size_t)p0 * DDIM;
        #pragma unroll
        for (int it = 0; it < 8; ++it) {
            int t = tid + it * BLOCKT;       // float4 index within 64x128 tile
            int row = t >> 5;                // 32 float4 per row
            int col = (t & 31) << 2;
            float4 v = *(const float4*)(src + row * DDIM + col);
            *(float4*)&r_lds[row][col] = v;
        }
    }

    float4 yreg[8];
    #pragma unroll
    for (int k = 0; k < 8; ++k) yreg[k] = make_float4(0.f, 0.f, 0.f, 0.f);

    float commit_part = 0.0f;

    for (int s = 0; s < NVQ; ++s) {
        const float* Ecb = cb + (size_t)s * KCODES * DDIM;
        const float* nrm = norms + s * KCODES;

        // ---- residual norms per point ----
        __syncthreads();   // r_lds fully written (load or previous update)
        {
            float acc = 0.0f;
            #pragma unroll
            for (int k = 0; k < 8; ++k) {
                float4 v = *(const float4*)&r_lds[pown][dq + 4 * k];
                acc += v.x * v.x + v.y * v.y + v.z * v.z + v.w * v.w;
            }
            part[tid] = acc;
        }
        __syncthreads();
        if (tid < TM)
            rnorm[tid] = (part[tid * 4] + part[tid * 4 + 1]) +
                         (part[tid * 4 + 2] + part[tid * 4 + 3]);

        float bd[4];
        int   bi[4];
        #pragma unroll
        for (int i = 0; i < 4; ++i) { bd[i] = FLT_MAX; bi[i] = 0x7fffffff; }

        for (int ch = 0; ch < NCHUNK; ++ch) {
            __syncthreads();   // protect e_lds reuse; makes rnorm visible (first iter)
            // ---- stage codebook chunk (64 codes x 128) into LDS ----
            {
                const float* src = Ecb + (size_t)ch * CHUNK * DDIM;
                #pragma unroll
                for (int it = 0; it < 8; ++it) {
                    int t = tid + it * BLOCKT;
                    int row = t >> 5;
                    int col = (t & 31) << 2;
                    float4 v = *(const float4*)(src + row * DDIM + col);
                    *(float4*)&e_lds[row][col] = v;
                }
                if (tid < CHUNK) cn[tid] = nrm[ch * CHUNK + tid];
            }
            __syncthreads();

            // ---- 64x64 score GEMM, 4x4 register tile, float4 multi-accumulators ----
            float4 acc[4][4];
            #pragma unroll
            for (int i = 0; i < 4; ++i)
                #pragma unroll
                for (int j = 0; j < 4; ++j) acc[i][j] = make_float4(0.f, 0.f, 0.f, 0.f);

            #pragma unroll 4
            for (int d = 0; d < DDIM; d += 4) {
                float4 rv[4], ev[4];
                #pragma unroll
                for (int i = 0; i < 4; ++i) rv[i] = *(const float4*)&r_lds[tp + 16 * i][d];
                #pragma unroll
                for (int j = 0; j < 4; ++j) ev[j] = *(const float4*)&e_lds[tc + 16 * j][d];
                #pragma unroll
                for (int i = 0; i < 4; ++i)
                    #pragma unroll
                    for (int j = 0; j < 4; ++j) {
                        acc[i][j].x += rv[i].x * ev[j].x;
                        acc[i][j].y += rv[i].y * ev[j].y;
                        acc[i][j].z += rv[i].z * ev[j].z;
                        acc[i][j].w += rv[i].w * ev[j].w;
                    }
            }

            #pragma unroll
            for (int i = 0; i < 4; ++i) {
                float rn = rnorm[tp + 16 * i];
                #pragma unroll
                for (int j = 0; j < 4; ++j) {
                    float dot  = (acc[i][j].x + acc[i][j].y) + (acc[i][j].z + acc[i][j].w);
                    float dist = (rn - 2.0f * dot) + cn[tc + 16 * j];
                    int c = ch * CHUNK + tc + 16 * j;
                    if (dist < bd[i]) { bd[i] = dist; bi[i] = c; }   // strict <: keeps lowest c on ties
                }
            }
        }

        // ---- cross-lane argmin over the 16 threads sharing each point ----
        #pragma unroll
        for (int i = 0; i < 4; ++i) {
            float d0 = bd[i];
            int   i0 = bi[i];
            #pragma unroll
            for (int m = 1; m < 16; m <<= 1) {
                float od = __shfl_xor(d0, m);
                int   oi = __shfl_xor(i0, m);
                if (od < d0 || (od == d0 && oi < i0)) { d0 = od; i0 = oi; }
            }
            if (tc == 0) besti_lds[tp + 16 * i] = i0;
        }
        __syncthreads();

        // ---- stage-0 index output ----
        if (s == 0 && tid < TM)
            out[(size_t)NPTS * DDIM + p0 + tid] = (float)besti_lds[tid];

        // ---- residual update + y accumulate (each thread owns point pown, quarter dq) ----
        {
            int c = besti_lds[pown];
            const float* q = Ecb + (size_t)c * DDIM + dq;
            #pragma unroll
            for (int k = 0; k < 8; ++k) {
                float4 qv = *(const float4*)(q + 4 * k);
                float4 rv = *(float4*)&r_lds[pown][dq + 4 * k];
                rv.x -= qv.x; rv.y -= qv.y; rv.z -= qv.z; rv.w -= qv.w;
                *(float4*)&r_lds[pown][dq + 4 * k] = rv;
                yreg[k].x += qv.x; yreg[k].y += qv.y; yreg[k].z += qv.z; yreg[k].w += qv.w;
                if (s == 0)
                    commit_part += rv.x * rv.x + rv.y * rv.y + rv.z * rv.z + rv.w * rv.w;
            }
        }
    }

    // ---- commit loss: block reduce + atomic ----
    __syncthreads();
    part[tid] = commit_part;
    __syncthreads();
    #pragma unroll
    for (int w = BLOCKT / 2; w >= 1; w >>= 1) {
        if (tid < w) part[tid] += part[tid + w];
        __syncthreads();
    }
    if (tid == 0)
        atomicAdd(out + (size_t)NPTS * DDIM + NPTS,
                  part[0] * (1.0f / ((float)NPTS * (float)DDIM)));

    // ---- final linear: out = y @ W^T + b ----
    // write y into r_lds (each thread its own region; chunk-loop sync publishes it)
    #pragma unroll
    for (int k = 0; k < 8; ++k) *(float4*)&r_lds[pown][dq + 4 * k] = yreg[k];

    for (int ch = 0; ch < 2; ++ch) {
        __syncthreads();
        {
            const float* src = W + (size_t)ch * CHUNK * DDIM;
            #pragma unroll
            for (int it = 0; it < 8; ++it) {
                int t = tid + it * BLOCKT;
                int row = t >> 5;
                int col = (t & 31) << 2;
                float4 v = *(const float4*)(src + row * DDIM + col);
                *(float4*)&e_lds[row][col] = v;
            }
            if (tid < CHUNK) cn[tid] = bias[ch * CHUNK + tid];
        }
        __syncthreads();

        float4 acc[4][4];
        #pragma unroll
        for (int i = 0; i < 4; ++i)
            #pragma unroll
            for (int j = 0; j < 4; ++j) acc[i][j] = make_float4(0.f, 0.f, 0.f, 0.f);

        #pragma unroll 4
        for (int d = 0; d < DDIM; d += 4) {
            float4 rv[4], ev[4];
            #pragma unroll
            for (int i = 0; i < 4; ++i) rv[i] = *(const float4*)&r_lds[tp + 16 * i][d];
            #pragma unroll
            for (int j = 0; j < 4; ++j) ev[j] = *(const float4*)&e_lds[tc + 16 * j][d];
            #pragma unroll
            for (int i = 0; i < 4; ++i)
                #pragma unroll
                for (int j = 0; j < 4; ++j) {
                    acc[i][j].x += rv[i].x * ev[j].x;
                    acc[i][j].y += rv[i].y * ev[j].y;
                    acc[i][j].z += rv[i].z * ev[j].z;
                    acc[i][j].w += rv[i].w * ev[j].w;
                }
        }

        #pragma unroll
        for (int i = 0; i < 4; ++i) {
            int p = p0 + tp + 16 * i;
            #pragma unroll
            for (int j = 0; j < 4; ++j) {
                int o = ch * CHUNK + tc + 16 * j;
                float dot = (acc[i][j].x + acc[i][j].y) + (acc[i][j].z + acc[i][j].w);
                out[(size_t)p * DDIM + o] = dot + cn[tc + 16 * j];
            }
        }
    }
}

// ---------------------------------------------------------------------------
extern "C" void kernel_launch(void* const* d_in, const int* in_sizes, int n_in,
                              void* d_out, int out_size, void* d_ws, size_t ws_size,
                              hipStream_t stream) {
    const float* x    = (const float*)d_in[0];
    const float* cb   = (const float*)d_in[1];
    const float* linw = (const float*)d_in[2];
    const float* linb = (const float*)d_in[3];
    float* out = (float*)d_out;
    float* norms = (float*)d_ws;   // NVQ*KCODES floats

    zero_commit_kernel<<<1, 1, 0, stream>>>(out + (size_t)NPTS * DDIM + NPTS);
    norms_kernel<<<NVQ * KCODES, 64, 0, stream>>>(cb, norms);
    rvq_kernel<<<NPTS / TM, BLOCKT, 0, stream>>>(x, cb, linw, linb, norms, out);
}

// Round 2
// 1182.995 us; speedup vs baseline: 3.1388x; 3.1388x over previous
//
#include <hip/hip_runtime.h>
#include <float.h>

typedef _Float16 f16;
typedef f16 f16x8 __attribute__((ext_vector_type(8)));
typedef float f32x4 __attribute__((ext_vector_type(4)));
typedef unsigned int u32;

#define NPTS 262144
#define DDIM 128
#define NVQ 6
#define KCODES 512
#define TM 64          // points per block
#define BLOCKT 256
#define CHUNKC 128     // codes staged per LDS chunk
#define NCHUNK (KCODES / CHUNKC)

// swizzled element index for f16 [rows][128] tiles, 16B-group granularity.
// grp = 16B group (8 f16) 0..15; XOR with row&7 kills the 16-way bank conflict
// on stride-256B fragment reads (2-way residue is free).
__device__ __forceinline__ int swz(int row, int grp) {
    return row * DDIM + ((grp ^ (row & 7)) << 3);
}

__device__ __forceinline__ f16x8 cvt8(float4 a, float4 b) {
    f16x8 h;
    h[0] = (f16)a.x; h[1] = (f16)a.y; h[2] = (f16)a.z; h[3] = (f16)a.w;
    h[4] = (f16)b.x; h[5] = (f16)b.y; h[6] = (f16)b.z; h[7] = (f16)b.w;
    return h;
}

// ---------------------------------------------------------------------------
__global__ void zero_commit_kernel(float* p) { *p = 0.0f; }

// norms[s*K + c] = sum_d E[s][c][d]^2 (fp32, one wave per code row)
__global__ void norms_kernel(const float* __restrict__ cb, float* __restrict__ norms) {
    int row = blockIdx.x;
    int lane = threadIdx.x;
    const float* r = cb + (size_t)row * DDIM;
    float2 v = *(const float2*)(r + lane * 2);
    float s = v.x * v.x + v.y * v.y;
    #pragma unroll
    for (int m = 32; m >= 1; m >>= 1) s += __shfl_xor(s, m);
    if (lane == 0) norms[row] = s;
}

// codebook fp32 -> fp16 (8 elems per thread)
__global__ void preconv_kernel(const float* __restrict__ cb, f16* __restrict__ cb16) {
    size_t base = ((size_t)blockIdx.x * 256 + threadIdx.x) * 8;
    float4 a = *(const float4*)(cb + base);
    float4 b = *(const float4*)(cb + base + 4);
    *(f16x8*)(cb16 + base) = cvt8(a, b);
}

// ---------------------------------------------------------------------------
// Fused residual-VQ (6 stages, MFMA fp16 scoring + fp32 top-2 rescue) + linear.
template<bool PRE>
__global__ __launch_bounds__(BLOCKT, 2)
void rvq_kernel(const float* __restrict__ x, const float* __restrict__ cb,
                const f16* __restrict__ cb16, const float* __restrict__ W,
                const float* __restrict__ bias, const float* __restrict__ norms,
                float* __restrict__ out) {
    __shared__ f16   rh[TM * DDIM];          // residual (or y) fp16, swizzled
    __shared__ f16   e_lds[CHUNKC * DDIM];   // code chunk / W fp16, swizzled
    __shared__ float cn[CHUNKC];             // code norms / bias
    __shared__ uint4 cand[4 * TM];           // per-wave top2 per point
    __shared__ uint2 besti2[TM];
    __shared__ float part[BLOCKT];

    const int tid  = threadIdx.x;
    const int wid  = tid >> 6;
    const int lane = tid & 63;
    const int g    = lane >> 4;      // k-group 0..3
    const int li   = lane & 15;      // row/col within 16-tile
    const int p_own = tid >> 2;      // owned point 0..63
    const int q     = tid & 3;       // owned d-quarter
    const int p0    = blockIdx.x * TM;

    // ---- load x quarter into registers ----
    float r[32];
    {
        const float* xs = x + (size_t)(p0 + p_own) * DDIM + q * 32;
        #pragma unroll
        for (int k = 0; k < 8; ++k) {
            float4 v = *(const float4*)(xs + 4 * k);
            r[4*k] = v.x; r[4*k+1] = v.y; r[4*k+2] = v.z; r[4*k+3] = v.w;
        }
    }
    // initial rh build (fp16 residual)
    #pragma unroll
    for (int k = 0; k < 4; ++k) {
        f16x8 h;
        #pragma unroll
        for (int m = 0; m < 8; ++m) h[m] = (f16)r[8*k+m];
        *(f16x8*)&rh[swz(p_own, q * 4 + k)] = h;
    }
    __syncthreads();

    float commit_part = 0.0f;

    for (int s = 0; s < NVQ; ++s) {
        // ---- B-fragments: residual fp16 in registers, reused over all 512 codes
        f16x8 Bf[4][4];   // [point-tile j][ks]
        #pragma unroll
        for (int j = 0; j < 4; ++j)
            #pragma unroll
            for (int ks = 0; ks < 4; ++ks)
                Bf[j][ks] = *(const f16x8*)&rh[swz(16 * j + li, ks * 4 + g)];

        float d1[4], d2[4]; u32 i1[4], i2[4];
        #pragma unroll
        for (int j = 0; j < 4; ++j) { d1[j] = FLT_MAX; d2[j] = FLT_MAX; i1[j] = 0xffffffffu; i2[j] = 0xffffffffu; }

        for (int ch = 0; ch < NCHUNK; ++ch) {
            __syncthreads();
            // ---- stage 128-code chunk into e_lds (fp16, swizzled) ----
            if (PRE) {
                const f16* src = cb16 + (size_t)(s * KCODES + ch * CHUNKC) * DDIM;
                #pragma unroll
                for (int it = 0; it < 8; ++it) {
                    int u = tid + it * BLOCKT; int row = u >> 4, grp = u & 15;
                    int4 v = *(const int4*)(src + row * DDIM + grp * 8);
                    *(int4*)&e_lds[swz(row, grp)] = v;
                }
            } else {
                const float* src = cb + (size_t)(s * KCODES + ch * CHUNKC) * DDIM;
                #pragma unroll
                for (int it = 0; it < 8; ++it) {
                    int u = tid + it * BLOCKT; int row = u >> 4, grp = u & 15;
                    const float* sp = src + row * DDIM + grp * 8;
                    float4 a = *(const float4*)sp;
                    float4 b = *(const float4*)(sp + 4);
                    *(f16x8*)&e_lds[swz(row, grp)] = cvt8(a, b);
                }
            }
            if (tid < CHUNKC) cn[tid] = norms[s * KCODES + ch * CHUNKC + tid];
            __syncthreads();

            // ---- MFMA: D[code][point], wave handles codes 32*wid..+31 (i=0..1)
            f32x4 acc[2][4];
            #pragma unroll
            for (int i = 0; i < 2; ++i)
                #pragma unroll
                for (int j = 0; j < 4; ++j) acc[i][j] = (f32x4)0.0f;

            #pragma unroll
            for (int ks = 0; ks < 4; ++ks)
                #pragma unroll
                for (int i = 0; i < 2; ++i) {
                    f16x8 A = *(const f16x8*)&e_lds[swz(32 * wid + 16 * i + li, ks * 4 + g)];
                    #pragma unroll
                    for (int j = 0; j < 4; ++j)
                        acc[i][j] = __builtin_amdgcn_mfma_f32_16x16x32_f16(A, Bf[j][ks], acc[i][j], 0, 0, 0);
                }

            // ---- epilogue: dist = ||E||^2 - 2 dot, insert into per-point top-2
            #pragma unroll
            for (int i = 0; i < 2; ++i) {
                int cl = 32 * wid + 16 * i + 4 * g;   // local code base for this lane's rows
                float4 en4 = *(const float4*)&cn[cl];
                #pragma unroll
                for (int j = 0; j < 4; ++j) {
                    #pragma unroll
                    for (int reg = 0; reg < 4; ++reg) {
                        float en = (reg == 0) ? en4.x : (reg == 1) ? en4.y : (reg == 2) ? en4.z : en4.w;
                        float dd = fmaf(-2.0f, acc[i][j][reg], en);
                        u32 cc = (u32)(ch * CHUNKC + cl + reg);
                        bool lt2 = (dd < d2[j]) || (dd == d2[j] && cc < i2[j]);
                        bool lt1 = (dd < d1[j]) || (dd == d1[j] && cc < i1[j]);
                        float nd2 = lt1 ? d1[j] : (lt2 ? dd : d2[j]);
                        u32  ni2 = lt1 ? i1[j] : (lt2 ? cc : i2[j]);
                        d1[j] = lt1 ? dd : d1[j];
                        i1[j] = lt1 ? cc : i1[j];
                        d2[j] = nd2; i2[j] = ni2;
                    }
                }
            }
        }

        // ---- in-wave merge across k-groups (lanes xor 16, 32) ----
        #pragma unroll
        for (int m = 16; m <= 32; m <<= 1) {
            #pragma unroll
            for (int j = 0; j < 4; ++j) {
                float b1 = __shfl_xor(d1[j], m); u32 bi1 = (u32)__shfl_xor((int)i1[j], m);
                float b2 = __shfl_xor(d2[j], m); u32 bi2 = (u32)__shfl_xor((int)i2[j], m);
                bool bf = (b1 < d1[j]) || (b1 == d1[j] && bi1 < i1[j]);
                float w1d = bf ? b1 : d1[j]; u32 w1i = bf ? bi1 : i1[j];
                float l1d = bf ? d1[j] : b1; u32 l1i = bf ? i1[j] : bi1;
                float s2d = bf ? b2 : d2[j]; u32 s2i = bf ? bi2 : i2[j];
                bool sf = (s2d < l1d) || (s2d == l1d && s2i < l1i);
                d1[j] = w1d; i1[j] = w1i;
                d2[j] = sf ? s2d : l1d; i2[j] = sf ? s2i : l1i;
            }
        }
        if (lane < 16) {
            #pragma unroll
            for (int j = 0; j < 4; ++j) {
                int p = 16 * j + li;
                cand[wid * TM + p] = make_uint4(__float_as_uint(d1[j]), i1[j],
                                                __float_as_uint(d2[j]), i2[j]);
            }
        }
        __syncthreads();

        // ---- cross-wave merge (each wave saw 1/4 of the codes) ----
        if (tid < TM) {
            float m1d = FLT_MAX, m2d = FLT_MAX; u32 m1i = 0xffffffffu, m2i = 0xffffffffu;
            #pragma unroll
            for (int w = 0; w < 4; ++w) {
                uint4 v = cand[w * TM + tid];
                float a1 = __uint_as_float(v.x); u32 ai1 = v.y;
                float a2 = __uint_as_float(v.z); u32 ai2 = v.w;
                bool bf = (a1 < m1d) || (a1 == m1d && ai1 < m1i);
                float w1d = bf ? a1 : m1d; u32 w1i = bf ? ai1 : m1i;
                float l1d = bf ? m1d : a1; u32 l1i = bf ? m1i : ai1;
                float s2d = bf ? a2 : m2d; u32 s2i = bf ? ai2 : m2i;
                bool sf = (s2d < l1d) || (s2d == l1d && s2i < l1i);
                m1d = w1d; m1i = w1i;
                m2d = sf ? s2d : l1d; m2i = sf ? s2i : l1i;
            }
            besti2[tid] = make_uint2(m1i, m2i);
        }
        __syncthreads();

        // ---- exact fp32 rescue: recompute both candidates, pick lex-min ----
        uint2 cc2 = besti2[p_own];
        int c1 = (int)cc2.x, c2 = (int)cc2.y;
        const float* E1 = cb + (size_t)(s * KCODES + c1) * DDIM + q * 32;
        const float* E2 = cb + (size_t)(s * KCODES + c2) * DDIM + q * 32;
        float dot1 = 0.0f, dot2 = 0.0f;
        #pragma unroll
        for (int k = 0; k < 8; ++k) {
            float4 a = *(const float4*)(E1 + 4 * k);
            dot1 += a.x * r[4*k] + a.y * r[4*k+1] + a.z * r[4*k+2] + a.w * r[4*k+3];
        }
        #pragma unroll
        for (int k = 0; k < 8; ++k) {
            float4 a = *(const float4*)(E2 + 4 * k);
            dot2 += a.x * r[4*k] + a.y * r[4*k+1] + a.z * r[4*k+2] + a.w * r[4*k+3];
        }
        dot1 += __shfl_xor(dot1, 1); dot1 += __shfl_xor(dot1, 2);
        dot2 += __shfl_xor(dot2, 1); dot2 += __shfl_xor(dot2, 2);
        float d1e = fmaf(-2.0f, dot1, norms[s * KCODES + c1]);
        float d2e = fmaf(-2.0f, dot2, norms[s * KCODES + c2]);
        int best = (d2e < d1e || (d2e == d1e && c2 < c1)) ? c2 : c1;

        if (s == 0 && q == 0)
            out[(size_t)NPTS * DDIM + p0 + p_own] = (float)best;

        // ---- exact residual update from fp32 code row ----
        {
            const float* Eb = cb + (size_t)(s * KCODES + best) * DDIM + q * 32;
            float cp = 0.0f;
            #pragma unroll
            for (int k = 0; k < 8; ++k) {
                float4 a = *(const float4*)(Eb + 4 * k);
                r[4*k]   -= a.x; r[4*k+1] -= a.y; r[4*k+2] -= a.z; r[4*k+3] -= a.w;
                cp += r[4*k]*r[4*k] + r[4*k+1]*r[4*k+1] + r[4*k+2]*r[4*k+2] + r[4*k+3]*r[4*k+3];
            }
            if (s == 0) commit_part = cp;
        }

        __syncthreads();   // everyone done with cand/besti2 and B-frag reads
        // ---- rebuild rh: residual fp16 (or y = x - r after last stage) ----
        if (s < NVQ - 1) {
            #pragma unroll
            for (int k = 0; k < 4; ++k) {
                f16x8 h;
                #pragma unroll
                for (int m = 0; m < 8; ++m) h[m] = (f16)r[8*k+m];
                *(f16x8*)&rh[swz(p_own, q * 4 + k)] = h;
            }
        } else {
            const float* xs = x + (size_t)(p0 + p_own) * DDIM + q * 32;
            #pragma unroll
            for (int k = 0; k < 4; ++k) {
                float4 a = *(const float4*)(xs + 8 * k);
                float4 b = *(const float4*)(xs + 8 * k + 4);
                float y0 = a.x - r[8*k+0], y1 = a.y - r[8*k+1], y2 = a.z - r[8*k+2], y3 = a.w - r[8*k+3];
                float y4 = b.x - r[8*k+4], y5 = b.y - r[8*k+5], y6 = b.z - r[8*k+6], y7 = b.w - r[8*k+7];
                f16x8 h;
                h[0]=(f16)y0; h[1]=(f16)y1; h[2]=(f16)y2; h[3]=(f16)y3;
                h[4]=(f16)y4; h[5]=(f16)y5; h[6]=(f16)y6; h[7]=(f16)y7;
                *(f16x8*)&rh[swz(p_own, q * 4 + k)] = h;
            }
        }
        __syncthreads();
    }

    // ---- final linear: out = y @ W^T + b (same MFMA path, A = W) ----
    {
        #pragma unroll
        for (int it = 0; it < 8; ++it) {
            int u = tid + it * BLOCKT; int row = u >> 4, grp = u & 15;
            const float* sp = W + row * DDIM + grp * 8;
            float4 a = *(const float4*)sp;
            float4 b = *(const float4*)(sp + 4);
            *(f16x8*)&e_lds[swz(row, grp)] = cvt8(a, b);
        }
        if (tid < CHUNKC) cn[tid] = bias[tid];
        __syncthreads();

        f16x8 Bf[4][4];
        #pragma unroll
        for (int j = 0; j < 4; ++j)
            #pragma unroll
            for (int ks = 0; ks < 4; ++ks)
                Bf[j][ks] = *(const f16x8*)&rh[swz(16 * j + li, ks * 4 + g)];

        f32x4 acc[2][4];
        #pragma unroll
        for (int i = 0; i < 2; ++i)
            #pragma unroll
            for (int j = 0; j < 4; ++j) acc[i][j] = (f32x4)0.0f;

        #pragma unroll
        for (int ks = 0; ks < 4; ++ks)
            #pragma unroll
            for (int i = 0; i < 2; ++i) {
                f16x8 A = *(const f16x8*)&e_lds[swz(32 * wid + 16 * i + li, ks * 4 + g)];
                #pragma unroll
                for (int j = 0; j < 4; ++j)
                    acc[i][j] = __builtin_amdgcn_mfma_f32_16x16x32_f16(A, Bf[j][ks], acc[i][j], 0, 0, 0);
            }

        #pragma unroll
        for (int i = 0; i < 2; ++i) {
            int obase = 32 * wid + 16 * i + 4 * g;
            float4 b4 = *(const float4*)&cn[obase];
            #pragma unroll
            for (int j = 0; j < 4; ++j) {
                int p = 16 * j + li;
                float4 o;
                o.x = acc[i][j][0] + b4.x;
                o.y = acc[i][j][1] + b4.y;
                o.z = acc[i][j][2] + b4.z;
                o.w = acc[i][j][3] + b4.w;
                *(float4*)(out + (size_t)(p0 + p) * DDIM + obase) = o;
            }
        }
    }

    // ---- commit loss reduce + atomic ----
    part[tid] = commit_part;
    __syncthreads();
    #pragma unroll
    for (int w = BLOCKT / 2; w >= 1; w >>= 1) {
        if (tid < w) part[tid] += part[tid + w];
        __syncthreads();
    }
    if (tid == 0)
        atomicAdd(out + (size_t)NPTS * DDIM + NPTS,
                  part[0] * (1.0f / ((float)NPTS * (float)DDIM)));
}

// ---------------------------------------------------------------------------
extern "C" void kernel_launch(void* const* d_in, const int* in_sizes, int n_in,
                              void* d_out, int out_size, void* d_ws, size_t ws_size,
                              hipStream_t stream) {
    const float* x    = (const float*)d_in[0];
    const float* cb   = (const float*)d_in[1];
    const float* linw = (const float*)d_in[2];
    const float* linb = (const float*)d_in[3];
    float* out  = (float*)d_out;
    float* norms = (float*)d_ws;                       // 3072 floats
    f16*  cb16  = (f16*)((char*)d_ws + 16384);         // 786432 B fp16 codebook
    const size_t need = 16384 + (size_t)NVQ * KCODES * DDIM * 2;

    zero_commit_kernel<<<1, 1, 0, stream>>>(out + (size_t)NPTS * DDIM + NPTS);
    norms_kernel<<<NVQ * KCODES, 64, 0, stream>>>(cb, norms);

    if (ws_size >= need) {
        preconv_kernel<<<(NVQ * KCODES * DDIM) / (256 * 8), 256, 0, stream>>>(cb, cb16);
        rvq_kernel<true><<<NPTS / TM, BLOCKT, 0, stream>>>(x, cb, cb16, linw, linb, norms, out);
    } else {
        rvq_kernel<false><<<NPTS / TM, BLOCKT, 0, stream>>>(x, cb, cb16, linw, linb, norms, out);
    }
}